// Round 13
// baseline (343.076 us; speedup 1.0000x reference)
//
#include <hip/hip_runtime.h>
#include <hip/hip_bf16.h>
#include <stdint.h>

namespace {

constexpr int kNX = 1024, kNY = 1024, kT = 512, kTP = 512, kD = 128, kC = 8;
constexpr int kK = kTP * kD;            // 65536 flattened contraction dim
constexpr int SPLITK = 16;
constexpr int KCH = kK / SPLITK;        // 4096 per z-slice
constexpr int BKT = 64;                 // K-tile depth
constexpr int NT = KCH / BKT;           // 64 K-tiles per block

typedef short bf16x8 __attribute__((ext_vector_type(8)));
typedef float f32x4 __attribute__((ext_vector_type(4)));
typedef unsigned int u32x4 __attribute__((ext_vector_type(4)));

// ---------------- workspace layout (bytes) ----------------
constexpr size_t OFF_YB  = 0;                                   // Y bf16   [NY][TP][D]  128MB
constexpr size_t OFF_XP  = OFF_YB + (size_t)kNY * kK * 2;       // XP bf16  [NX][TP][D]  128MB
constexpr size_t OFF_TS  = OFF_XP + (size_t)kNX * kK * 2;       // ts i32   [C][TP]
constexpr size_t OFF_TE  = OFF_TS + (size_t)kC * kTP * 4;       // te i32   [C][TP]
constexpr size_t OFF_C1  = OFF_TE + (size_t)kC * kTP * 4;       // C1 f32   [NX]
constexpr size_t OFF_C2  = OFF_C1 + (size_t)kNX * 4;            // C2 f32   [C][NY]

__device__ __forceinline__ void gload16(const __hip_bfloat16* g, __hip_bfloat16* l) {
    __builtin_amdgcn_global_load_lds(
        (const __attribute__((address_space(1))) unsigned int*)g,
        (__attribute__((address_space(3))) unsigned int*)l, 16, 0, 0);
}

__device__ __forceinline__ unsigned short bf(float x) {
    union { __hip_bfloat16 h; unsigned short u; } cv;
    cv.h = __float2bfloat16(x);
    return cv.u;
}

// ---- init: ts=INT_MAX, te=-1, C1=0 ----
__global__ void init_ranges(int* __restrict__ ts, int* __restrict__ te,
                            float* __restrict__ C1) {
    const int idx = blockIdx.x * 256 + threadIdx.x;
    if (idx < kC * kTP) { ts[idx] = 0x7fffffff; te[idx] = -1; }
    if (idx < kNX) C1[idx] = 0.f;
}

// ---- pi scan: per-column contiguous run [ts,te] of the 0/1 monotone path ----
__global__ void pi_scan(const float* __restrict__ pi, int* __restrict__ ts,
                        int* __restrict__ te) {
    const int c = blockIdx.y;
    const int tbase = blockIdx.x * 64;
    const int p = threadIdx.x;                  // 512 threads, one per column
    const float* pic = pi + (size_t)c * kT * kTP;
    int tmin = 0x7fffffff, tmax = -1;
    for (int tt = 0; tt < 64; ++tt) {
        const int t = tbase + tt;
        float v = pic[(size_t)t * kTP + p];     // coalesced across p
        if (v != 0.f) { if (t < tmin) tmin = t; tmax = t; }
    }
    if (tmax >= 0) {
        atomicMin(&ts[c * kTP + p], tmin);
        atomicMax(&te[c * kTP + p], tmax);
    }
}

// ---- fused prep (r12 structure + nontemporal streams) ----
// Y-part (bid < NY): Y->bf16 convert; C2 via per-lane algebra. Y reads and
// YB writes NONTEMPORAL: Y/YB are streamed once here; keeping them out of
// L2/L3 preserves cache for X (intra-block reuse) and cuts write-allocate
// turnaround on the mixed read+write stream.
// XP-part (bid >= NY): XCD-affinity grid; contiguous row range staged to LDS
// in 64-row windows (flat float4 copy); XPB writes nontemporal.
__global__ __launch_bounds__(256) void prep_main(const float* __restrict__ Y,
                                                 const float* __restrict__ X,
                                                 const int* __restrict__ classe,
                                                 const int* __restrict__ ts,
                                                 const int* __restrict__ te,
                                                 __hip_bfloat16* __restrict__ YB,
                                                 __hip_bfloat16* __restrict__ XPB,
                                                 float* __restrict__ C1,
                                                 float* __restrict__ C2) {
    __shared__ __align__(16) char smem[32768];  // union: cntT (16KB) | window (32KB)
    const int bid = blockIdx.x;
    const int tid = threadIdx.x;
    const int sub = tid & 31, g = tid >> 5;     // 8 groups of 32 lanes

    if (bid < kNY) {
        // ================= Y-part: j = bid =================
        const int j = bid;
        float (*cntT)[kC] = (float (*)[kC])smem;    // [p][c], 16KB
        for (int idx = tid; idx < kTP * kC; idx += 256) {
            const int p = idx >> 3, c = idx & 7;    // LDS writes consecutive
            cntT[p][c] = (float)(te[c * kTP + p] - ts[c * kTP + p] + 1);
        }
        __syncthreads();

        const int si = tid & 15;                // 16 lanes per row (8 floats each)
        const int rg = tid >> 4;                // 16 rows per iteration
        const float* Yj = Y + (size_t)j * kTP * kD;
        unsigned short* YBj = (unsigned short*)YB + (size_t)j * kTP * kD;
        float c2acc[8] = {};
        for (int it = 0; it < 32; ++it) {
            const int p = it * 16 + rg;
            const f32x4* src = (const f32x4*)(Yj + (size_t)p * kD + si * 8);
            f32x4 v0 = __builtin_nontemporal_load(src);
            f32x4 v1 = __builtin_nontemporal_load(src + 1);
            u32x4 o;
            o.x = ((unsigned)bf(v0.y) << 16) | bf(v0.x);
            o.y = ((unsigned)bf(v0.w) << 16) | bf(v0.z);
            o.z = ((unsigned)bf(v1.y) << 16) | bf(v1.x);
            o.w = ((unsigned)bf(v1.w) << 16) | bf(v1.z);
            __builtin_nontemporal_store(o, (u32x4*)(YBj + (size_t)p * kD + si * 8));
            float s = v0.x * v0.x + v0.y * v0.y + v0.z * v0.z + v0.w * v0.w
                    + v1.x * v1.x + v1.y * v1.y + v1.z * v1.z + v1.w * v1.w;
            const f32x4* cw = (const f32x4*)&cntT[p][0];
            f32x4 c0 = cw[0], c1 = cw[1];
            c2acc[0] += c0.x * s; c2acc[1] += c0.y * s;
            c2acc[2] += c0.z * s; c2acc[3] += c0.w * s;
            c2acc[4] += c1.x * s; c2acc[5] += c1.y * s;
            c2acc[6] += c1.z * s; c2acc[7] += c1.w * s;
        }
        // one-time reduction: butterfly within wave, LDS across waves
        #pragma unroll
        for (int c = 0; c < 8; ++c)
            #pragma unroll
            for (int off = 32; off; off >>= 1)
                c2acc[c] += __shfl_down(c2acc[c], off);
        __shared__ float c2w[4][8];
        if ((tid & 63) == 0) {
            #pragma unroll
            for (int c = 0; c < 8; ++c) c2w[tid >> 6][c] = c2acc[c];
        }
        __syncthreads();
        if (tid < 8)
            C2[tid * kNY + j] = c2w[0][tid] + c2w[1][tid] + c2w[2][tid] + c2w[3][tid];
    } else {
        // ================= XP-part: sample i, p-chunk pc =================
        const int b2 = bid - kNY;
        const int x8 = b2 & 7, r = b2 >> 3;
        const int pc = r & 7, i = (r >> 3) * 8 + x8;   // b2%8 == i%8 -> XCD affinity
        const int c = classe[i];
        const f32x4* Xi = (const f32x4*)(X + (size_t)i * kT * kD);
        unsigned short* XPi = (unsigned short*)XPB + (size_t)i * kTP * kD;
        int t0v[8], t1v[8];
        #pragma unroll
        for (int q = 0; q < 8; ++q) {
            const int p = pc * 64 + q * 8 + g;
            t0v[q] = ts[c * kTP + p];
            t1v[q] = te[c * kTP + p];
        }
        const int t_lo = ts[c * kTP + pc * 64];        // monotone: block min
        const int t_hi = te[c * kTP + pc * 64 + 63];   // monotone: block max
        f32x4* ldsW = (f32x4*)smem;                    // 64 rows x 512B
        float ax[8] = {}, ay[8] = {}, az[8] = {}, aw[8] = {};
        float sq = 0.f;
        for (int w0 = t_lo; w0 <= t_hi; w0 += 64) {
            const int w1 = min(w0 + 63, t_hi);
            const int n4 = (w1 - w0 + 1) * 32;
            __syncthreads();                           // prior window consumed
            const f32x4* src = Xi + (size_t)w0 * 32;   // flat contiguous copy
            for (int idx = tid; idx < n4; idx += 256) ldsW[idx] = src[idx];
            __syncthreads();
            #pragma unroll
            for (int q = 0; q < 8; ++q) {
                const int ta = max(t0v[q], w0), tb = min(t1v[q], w1);
                for (int t = ta; t <= tb; ++t) {
                    f32x4 v = ldsW[(t - w0) * 32 + sub];
                    ax[q] += v.x; ay[q] += v.y; az[q] += v.z; aw[q] += v.w;
                    sq += v.x * v.x + v.y * v.y + v.z * v.z + v.w * v.w;
                }
            }
        }
        #pragma unroll
        for (int q = 0; q < 8; ++q) {
            const int p = pc * 64 + q * 8 + g;
            u32x4 o2;
            o2.x = ((unsigned)bf(ay[q]) << 16) | bf(ax[q]);
            o2.y = ((unsigned)bf(aw[q]) << 16) | bf(az[q]);
            // write 8B via two dwords packed in x,y; use 8-byte store
            unsigned long long pk = ((unsigned long long)o2.y << 32) | o2.x;
            __builtin_nontemporal_store(pk, (unsigned long long*)(XPi + p * kD + sub * 4));
        }
        #pragma unroll
        for (int o = 32; o; o >>= 1) sq += __shfl_down(sq, o);
        __shared__ float red[4];
        if ((tid & 63) == 0) red[tid >> 6] = sq;
        __syncthreads();
        if (tid == 0) atomicAdd(&C1[i], red[0] + red[1] + red[2] + red[3]);
    }
}

// ---- out init: C1[i] + C2[classe[i]][j] ----
__global__ void init_out(const float* __restrict__ C1, const float* __restrict__ C2,
                         const int* __restrict__ classe, float* __restrict__ out) {
    const int i = blockIdx.x;
    const float c1 = C1[i];
    const float* c2 = C2 + (size_t)classe[i] * kNY;
    float* o = out + (size_t)i * kNY;
    for (int j = threadIdx.x; j < kNY; j += 256) o[j] = c1 + c2[j];
}

// ---- C3 GEMM: out -= 2 * XP @ Y^T ----  (round-4/7/9/12 kernel: measured best)
// 256x256 tile, BKT=64, 8 waves (2x4, 128x64 each), whole-tile LDS double
// buffer (128KB), ONE vmcnt(0)+barrier per K-tile, qd-interleaved inner loop,
// XOR-swizzled LDS, split-K=16 fp32 atomic epilogue, XCD-aware grid swizzle.
__global__ __launch_bounds__(512, 2) void gemm_c3(const __hip_bfloat16* __restrict__ A,
                                                  const __hip_bfloat16* __restrict__ B,
                                                  float* __restrict__ out) {
    __shared__ __align__(16) char lds[131072];   // [buf][A 32KB | B 32KB]
    __hip_bfloat16* ldsE = (__hip_bfloat16*)lds;

    const int tid = threadIdx.x;
    const int lane = tid & 63, wv = tid >> 6;
    const int wr = wv >> 2, wc = wv & 3;         // 2x4 wave grid

    // XCD swizzle: 256 blocks, 8 XCDs -> 32 consecutive logical ids per XCD
    const int bid = blockIdx.x;
    const int swz = (bid & 7) * 32 + (bid >> 3);
    const int z = swz >> 4, t16 = swz & 15;
    const int rowBase = (t16 >> 2) * 256;
    const int colBase = (t16 & 3) * 256;
    const size_t k0base = (size_t)z * KCH;

    // ---- staging source addresses (per lane, per q-chunk) ----
    const int scol = ((tid & 7) * 8) ^ (((tid >> 3) & 7) * 8);   // elements
    const __hip_bfloat16* aSrc[4];
    const __hip_bfloat16* bSrc[4];
    int dstE[4];
    #pragma unroll
    for (int q = 0; q < 4; ++q) {
        const int R = q * 64 + (tid >> 3);
        aSrc[q] = A + (size_t)(rowBase + R) * kK + k0base + scol;
        bSrc[q] = B + (size_t)(colBase + R) * kK + k0base + scol;
        dstE[q] = (q * 512 + tid) * 8;
    }

    // ---- ds_read base addresses (bytes within a buffer), read-side XOR ----
    const int swzR = (lane & 7) << 4;
    const int aLin = (wr * 128 + (lane & 15)) * 128 + ((lane >> 4) << 4);
    const int bLin = (wc * 64 + (lane & 15)) * 128 + ((lane >> 4) << 4);
    const int aB0 = (aLin) ^ swzR, aB1 = (aLin + 64) ^ swzR;     // ks=0/1
    const int bB0 = (bLin) ^ swzR, bB1 = (bLin + 64) ^ swzR;

    f32x4 acc[8][4] = {};

    // prologue: stage tile 0 into buf 0
    #pragma unroll
    for (int q = 0; q < 4; ++q) gload16(aSrc[q], ldsE + dstE[q]);
    #pragma unroll
    for (int q = 0; q < 4; ++q) gload16(bSrc[q], ldsE + 16384 + dstE[q]);

    int buf = 0;
    for (int t = 0; t < NT; ++t) {
        asm volatile("s_waitcnt vmcnt(0)" ::: "memory");
        __builtin_amdgcn_s_barrier();
        asm volatile("" ::: "memory");

        const int koff = (t + 1) * BKT;
        const int bufB = buf * 65536;            // byte offset of current buffer
        const int nBufE = (buf ^ 1) * 32768;     // element offset of next buffer

        if (t + 1 < NT) {                        // stage A of tile t+1
            #pragma unroll
            for (int q = 0; q < 4; ++q) gload16(aSrc[q] + koff, ldsE + nBufE + dstE[q]);
        }

        #pragma unroll
        for (int qd = 0; qd < 4; ++qd) {
            const int mh = qd & 1, nh = qd >> 1;
            bf16x8 af[4][2], bfr[2][2];
            #pragma unroll
            for (int m = 0; m < 4; ++m) {
                af[m][0] = *(const bf16x8*)(lds + bufB + aB0 + mh * 8192 + m * 2048);
                af[m][1] = *(const bf16x8*)(lds + bufB + aB1 + mh * 8192 + m * 2048);
            }
            #pragma unroll
            for (int n = 0; n < 2; ++n) {
                bfr[n][0] = *(const bf16x8*)(lds + bufB + 32768 + bB0 + nh * 4096 + n * 2048);
                bfr[n][1] = *(const bf16x8*)(lds + bufB + 32768 + bB1 + nh * 4096 + n * 2048);
            }
            __builtin_amdgcn_s_setprio(1);
            #pragma unroll
            for (int m = 0; m < 4; ++m)
                #pragma unroll
                for (int n = 0; n < 2; ++n) {
                    acc[mh * 4 + m][nh * 2 + n] = __builtin_amdgcn_mfma_f32_16x16x32_bf16(
                        af[m][0], bfr[n][0], acc[mh * 4 + m][nh * 2 + n], 0, 0, 0);
                    acc[mh * 4 + m][nh * 2 + n] = __builtin_amdgcn_mfma_f32_16x16x32_bf16(
                        af[m][1], bfr[n][1], acc[mh * 4 + m][nh * 2 + n], 0, 0, 0);
                }
            __builtin_amdgcn_s_setprio(0);

            if (qd == 0 && t + 1 < NT) {         // stage B of tile t+1
                #pragma unroll
                for (int q = 0; q < 4; ++q)
                    gload16(bSrc[q] + koff, ldsE + nBufE + 16384 + dstE[q]);
            }
        }
        buf ^= 1;
    }

    // epilogue: out -= 2*acc  (fp32 atomics; split-K partials race benignly)
    #pragma unroll
    for (int mi = 0; mi < 8; ++mi) {
        #pragma unroll
        for (int ni = 0; ni < 4; ++ni) {
            #pragma unroll
            for (int jj = 0; jj < 4; ++jj) {
                const int R = rowBase + wr * 128 + mi * 16 + (lane >> 4) * 4 + jj;
                const int Cc = colBase + wc * 64 + ni * 16 + (lane & 15);
                atomicAdd(&out[(size_t)R * kNY + Cc], -2.0f * acc[mi][ni][jj]);
            }
        }
    }
}

} // namespace

extern "C" void kernel_launch(void* const* d_in, const int* in_sizes, int n_in,
                              void* d_out, int out_size, void* d_ws, size_t ws_size,
                              hipStream_t stream) {
    const float* X = (const float*)d_in[0];
    const float* Y = (const float*)d_in[1];
    const float* pi = (const float*)d_in[2];
    const int* classe = (const int*)d_in[3];
    float* out = (float*)d_out;

    char* ws = (char*)d_ws;
    __hip_bfloat16* YB = (__hip_bfloat16*)(ws + OFF_YB);
    __hip_bfloat16* XPB = (__hip_bfloat16*)(ws + OFF_XP);
    int* ts = (int*)(ws + OFF_TS);
    int* te = (int*)(ws + OFF_TE);
    float* C1 = (float*)(ws + OFF_C1);
    float* C2 = (float*)(ws + OFF_C2);

    init_ranges<<<(kC * kTP + 255) / 256, 256, 0, stream>>>(ts, te, C1);
    pi_scan<<<dim3(kT / 64, kC), kTP, 0, stream>>>(pi, ts, te);
    prep_main<<<kNY + kNX * 8, 256, 0, stream>>>(Y, X, classe, ts, te, YB, XPB, C1, C2);
    init_out<<<kNX, 256, 0, stream>>>(C1, C2, classe, out);
    gemm_c3<<<(kNX / 256) * (kNY / 256) * SPLITK, 512, 0, stream>>>(XPB, YB, out);
}

// Round 14
// 329.482 us; speedup vs baseline: 1.0413x; 1.0413x over previous
//
#include <hip/hip_runtime.h>
#include <hip/hip_bf16.h>
#include <stdint.h>

namespace {

constexpr int kNX = 1024, kNY = 1024, kT = 512, kTP = 512, kD = 128, kC = 8;
constexpr int kK = kTP * kD;            // 65536 flattened contraction dim
constexpr int SPLITK = 16;
constexpr int KCH = kK / SPLITK;        // 4096 per z-slice
constexpr int BKT = 64;                 // K-tile depth
constexpr int NT = KCH / BKT;           // 64 K-tiles per block

typedef short bf16x8 __attribute__((ext_vector_type(8)));
typedef float f32x4 __attribute__((ext_vector_type(4)));

// ---------------- workspace layout (bytes) ----------------
constexpr size_t OFF_YB  = 0;                                   // Y bf16   [NY][TP][D]  128MB
constexpr size_t OFF_XP  = OFF_YB + (size_t)kNY * kK * 2;       // XP bf16  [NX][TP][D]  128MB
constexpr size_t OFF_TS  = OFF_XP + (size_t)kNX * kK * 2;       // ts i32   [C][TP]
constexpr size_t OFF_TE  = OFF_TS + (size_t)kC * kTP * 4;       // te i32   [C][TP]
constexpr size_t OFF_C1  = OFF_TE + (size_t)kC * kTP * 4;       // C1 f32   [NX]
constexpr size_t OFF_C2  = OFF_C1 + (size_t)kNX * 4;            // C2 f32   [C][NY]

__device__ __forceinline__ void gload16(const __hip_bfloat16* g, __hip_bfloat16* l) {
    __builtin_amdgcn_global_load_lds(
        (const __attribute__((address_space(1))) unsigned int*)g,
        (__attribute__((address_space(3))) unsigned int*)l, 16, 0, 0);
}

__device__ __forceinline__ unsigned short bf(float x) {
    union { __hip_bfloat16 h; unsigned short u; } cv;
    cv.h = __float2bfloat16(x);
    return cv.u;
}

// ---- init: ts=INT_MAX, te=-1, C1=0 ----
__global__ void init_ranges(int* __restrict__ ts, int* __restrict__ te,
                            float* __restrict__ C1) {
    const int idx = blockIdx.x * 256 + threadIdx.x;
    if (idx < kC * kTP) { ts[idx] = 0x7fffffff; te[idx] = -1; }
    if (idx < kNX) C1[idx] = 0.f;
}

// ---- pi scan: per-column contiguous run [ts,te] of the 0/1 monotone path ----
__global__ void pi_scan(const float* __restrict__ pi, int* __restrict__ ts,
                        int* __restrict__ te) {
    const int c = blockIdx.y;
    const int tbase = blockIdx.x * 64;
    const int p = threadIdx.x;                  // 512 threads, one per column
    const float* pic = pi + (size_t)c * kT * kTP;
    int tmin = 0x7fffffff, tmax = -1;
    for (int tt = 0; tt < 64; ++tt) {
        const int t = tbase + tt;
        float v = pic[(size_t)t * kTP + p];     // coalesced across p
        if (v != 0.f) { if (t < tmin) tmin = t; tmax = t; }
    }
    if (tmax >= 0) {
        atomicMin(&ts[c * kTP + p], tmin);
        atomicMax(&te[c * kTP + p], tmax);
    }
}

// ---- fused prep (r12 structure: measured best) ----
// Y-part (bid < NY): Y->bf16 convert; C2 via per-lane algebra (no shuffles).
// XP-part (bid >= NY): XCD-affinity grid; contiguous row range staged to LDS
// in 64-row windows (flat float4 copy -> max MLP, each row fetched once);
// runs gather at LDS speed. NO nontemporal hints: YB/XPB must stay L3-resident
// for the gemm (r13 lesson: nt stores cost the gemm ~13us).
__global__ __launch_bounds__(256) void prep_main(const float* __restrict__ Y,
                                                 const float* __restrict__ X,
                                                 const int* __restrict__ classe,
                                                 const int* __restrict__ ts,
                                                 const int* __restrict__ te,
                                                 __hip_bfloat16* __restrict__ YB,
                                                 __hip_bfloat16* __restrict__ XPB,
                                                 float* __restrict__ C1,
                                                 float* __restrict__ C2) {
    __shared__ __align__(16) char smem[32768];  // union: cntT (16KB) | window (32KB)
    const int bid = blockIdx.x;
    const int tid = threadIdx.x;
    const int sub = tid & 31, g = tid >> 5;     // 8 groups of 32 lanes

    if (bid < kNY) {
        // ================= Y-part: j = bid =================
        const int j = bid;
        float (*cntT)[kC] = (float (*)[kC])smem;    // [p][c], 16KB
        for (int idx = tid; idx < kTP * kC; idx += 256) {
            const int p = idx >> 3, c = idx & 7;    // LDS writes consecutive
            cntT[p][c] = (float)(te[c * kTP + p] - ts[c * kTP + p] + 1);
        }
        __syncthreads();

        const int si = tid & 15;                // 16 lanes per row (8 floats each)
        const int rg = tid >> 4;                // 16 rows per iteration
        const float* Yj = Y + (size_t)j * kTP * kD;
        unsigned short* YBj = (unsigned short*)YB + (size_t)j * kTP * kD;
        float c2acc[8] = {};
        for (int it = 0; it < 32; ++it) {
            const int p = it * 16 + rg;
            const float4* src = (const float4*)(Yj + (size_t)p * kD + si * 8);
            float4 v0 = src[0], v1 = src[1];
            union { ushort4 h[2]; uint4 q; } o;
            o.h[0].x = bf(v0.x); o.h[0].y = bf(v0.y); o.h[0].z = bf(v0.z); o.h[0].w = bf(v0.w);
            o.h[1].x = bf(v1.x); o.h[1].y = bf(v1.y); o.h[1].z = bf(v1.z); o.h[1].w = bf(v1.w);
            *(uint4*)(YBj + (size_t)p * kD + si * 8) = o.q;
            float s = v0.x * v0.x + v0.y * v0.y + v0.z * v0.z + v0.w * v0.w
                    + v1.x * v1.x + v1.y * v1.y + v1.z * v1.z + v1.w * v1.w;
            const float4* cw = (const float4*)&cntT[p][0];
            float4 c0 = cw[0], c1 = cw[1];
            c2acc[0] += c0.x * s; c2acc[1] += c0.y * s;
            c2acc[2] += c0.z * s; c2acc[3] += c0.w * s;
            c2acc[4] += c1.x * s; c2acc[5] += c1.y * s;
            c2acc[6] += c1.z * s; c2acc[7] += c1.w * s;
        }
        // one-time reduction: butterfly within wave, LDS across waves
        #pragma unroll
        for (int c = 0; c < 8; ++c)
            #pragma unroll
            for (int off = 32; off; off >>= 1)
                c2acc[c] += __shfl_down(c2acc[c], off);
        __shared__ float c2w[4][8];
        if ((tid & 63) == 0) {
            #pragma unroll
            for (int c = 0; c < 8; ++c) c2w[tid >> 6][c] = c2acc[c];
        }
        __syncthreads();
        if (tid < 8)
            C2[tid * kNY + j] = c2w[0][tid] + c2w[1][tid] + c2w[2][tid] + c2w[3][tid];
    } else {
        // ================= XP-part: sample i, p-chunk pc =================
        const int b2 = bid - kNY;
        const int x8 = b2 & 7, r = b2 >> 3;
        const int pc = r & 7, i = (r >> 3) * 8 + x8;   // b2%8 == i%8 -> XCD affinity
        const int c = classe[i];
        const float4* Xi = (const float4*)(X + (size_t)i * kT * kD);
        unsigned short* XPi = (unsigned short*)XPB + (size_t)i * kTP * kD;
        int t0v[8], t1v[8];
        #pragma unroll
        for (int q = 0; q < 8; ++q) {
            const int p = pc * 64 + q * 8 + g;
            t0v[q] = ts[c * kTP + p];
            t1v[q] = te[c * kTP + p];
        }
        const int t_lo = ts[c * kTP + pc * 64];        // monotone: block min
        const int t_hi = te[c * kTP + pc * 64 + 63];   // monotone: block max
        float4* ldsW = (float4*)smem;                  // 64 rows x 512B
        float ax[8] = {}, ay[8] = {}, az[8] = {}, aw[8] = {};
        float sq = 0.f;
        for (int w0 = t_lo; w0 <= t_hi; w0 += 64) {
            const int w1 = min(w0 + 63, t_hi);
            const int n4 = (w1 - w0 + 1) * 32;
            __syncthreads();                           // prior window consumed
            const float4* src = Xi + (size_t)w0 * 32;  // flat contiguous copy
            for (int idx = tid; idx < n4; idx += 256) ldsW[idx] = src[idx];
            __syncthreads();
            #pragma unroll
            for (int q = 0; q < 8; ++q) {
                const int ta = max(t0v[q], w0), tb = min(t1v[q], w1);
                for (int t = ta; t <= tb; ++t) {
                    float4 v = ldsW[(t - w0) * 32 + sub];
                    ax[q] += v.x; ay[q] += v.y; az[q] += v.z; aw[q] += v.w;
                    sq += v.x * v.x + v.y * v.y + v.z * v.z + v.w * v.w;
                }
            }
        }
        #pragma unroll
        for (int q = 0; q < 8; ++q) {
            const int p = pc * 64 + q * 8 + g;
            ushort4 o;
            o.x = bf(ax[q]); o.y = bf(ay[q]); o.z = bf(az[q]); o.w = bf(aw[q]);
            *(ushort4*)(XPi + p * kD + sub * 4) = o;
        }
        #pragma unroll
        for (int o = 32; o; o >>= 1) sq += __shfl_down(sq, o);
        __shared__ float red[4];
        if ((tid & 63) == 0) red[tid >> 6] = sq;
        __syncthreads();
        if (tid == 0) atomicAdd(&C1[i], red[0] + red[1] + red[2] + red[3]);
    }
}

// ---- out init: C1[i] + C2[classe[i]][j]  (float4: one vec per thread) ----
__global__ void init_out(const float* __restrict__ C1, const float* __restrict__ C2,
                         const int* __restrict__ classe, float* __restrict__ out) {
    const int i = blockIdx.x;
    const float c1 = C1[i];
    const float4* c2 = (const float4*)(C2 + (size_t)classe[i] * kNY);
    float4* o = (float4*)(out + (size_t)i * kNY);
    const int j = threadIdx.x;                  // kNY/4 == 256 == blockDim
    float4 v = c2[j];
    v.x += c1; v.y += c1; v.z += c1; v.w += c1;
    o[j] = v;
}

// ---- C3 GEMM: out -= 2 * XP @ Y^T ----  (round-4/7/9/12 kernel: measured best)
// 256x256 tile, BKT=64, 8 waves (2x4, 128x64 each), whole-tile LDS double
// buffer (128KB), ONE vmcnt(0)+barrier per K-tile, qd-interleaved inner loop,
// XOR-swizzled LDS, split-K=16 fp32 atomic epilogue, XCD-aware grid swizzle.
__global__ __launch_bounds__(512, 2) void gemm_c3(const __hip_bfloat16* __restrict__ A,
                                                  const __hip_bfloat16* __restrict__ B,
                                                  float* __restrict__ out) {
    __shared__ __align__(16) char lds[131072];   // [buf][A 32KB | B 32KB]
    __hip_bfloat16* ldsE = (__hip_bfloat16*)lds;

    const int tid = threadIdx.x;
    const int lane = tid & 63, wv = tid >> 6;
    const int wr = wv >> 2, wc = wv & 3;         // 2x4 wave grid

    // XCD swizzle: 256 blocks, 8 XCDs -> 32 consecutive logical ids per XCD
    const int bid = blockIdx.x;
    const int swz = (bid & 7) * 32 + (bid >> 3);
    const int z = swz >> 4, t16 = swz & 15;
    const int rowBase = (t16 >> 2) * 256;
    const int colBase = (t16 & 3) * 256;
    const size_t k0base = (size_t)z * KCH;

    // ---- staging source addresses (per lane, per q-chunk) ----
    const int scol = ((tid & 7) * 8) ^ (((tid >> 3) & 7) * 8);   // elements
    const __hip_bfloat16* aSrc[4];
    const __hip_bfloat16* bSrc[4];
    int dstE[4];
    #pragma unroll
    for (int q = 0; q < 4; ++q) {
        const int R = q * 64 + (tid >> 3);
        aSrc[q] = A + (size_t)(rowBase + R) * kK + k0base + scol;
        bSrc[q] = B + (size_t)(colBase + R) * kK + k0base + scol;
        dstE[q] = (q * 512 + tid) * 8;
    }

    // ---- ds_read base addresses (bytes within a buffer), read-side XOR ----
    const int swzR = (lane & 7) << 4;
    const int aLin = (wr * 128 + (lane & 15)) * 128 + ((lane >> 4) << 4);
    const int bLin = (wc * 64 + (lane & 15)) * 128 + ((lane >> 4) << 4);
    const int aB0 = (aLin) ^ swzR, aB1 = (aLin + 64) ^ swzR;     // ks=0/1
    const int bB0 = (bLin) ^ swzR, bB1 = (bLin + 64) ^ swzR;

    f32x4 acc[8][4] = {};

    // prologue: stage tile 0 into buf 0
    #pragma unroll
    for (int q = 0; q < 4; ++q) gload16(aSrc[q], ldsE + dstE[q]);
    #pragma unroll
    for (int q = 0; q < 4; ++q) gload16(bSrc[q], ldsE + 16384 + dstE[q]);

    int buf = 0;
    for (int t = 0; t < NT; ++t) {
        asm volatile("s_waitcnt vmcnt(0)" ::: "memory");
        __builtin_amdgcn_s_barrier();
        asm volatile("" ::: "memory");

        const int koff = (t + 1) * BKT;
        const int bufB = buf * 65536;            // byte offset of current buffer
        const int nBufE = (buf ^ 1) * 32768;     // element offset of next buffer

        if (t + 1 < NT) {                        // stage A of tile t+1
            #pragma unroll
            for (int q = 0; q < 4; ++q) gload16(aSrc[q] + koff, ldsE + nBufE + dstE[q]);
        }

        #pragma unroll
        for (int qd = 0; qd < 4; ++qd) {
            const int mh = qd & 1, nh = qd >> 1;
            bf16x8 af[4][2], bfr[2][2];
            #pragma unroll
            for (int m = 0; m < 4; ++m) {
                af[m][0] = *(const bf16x8*)(lds + bufB + aB0 + mh * 8192 + m * 2048);
                af[m][1] = *(const bf16x8*)(lds + bufB + aB1 + mh * 8192 + m * 2048);
            }
            #pragma unroll
            for (int n = 0; n < 2; ++n) {
                bfr[n][0] = *(const bf16x8*)(lds + bufB + 32768 + bB0 + nh * 4096 + n * 2048);
                bfr[n][1] = *(const bf16x8*)(lds + bufB + 32768 + bB1 + nh * 4096 + n * 2048);
            }
            __builtin_amdgcn_s_setprio(1);
            #pragma unroll
            for (int m = 0; m < 4; ++m)
                #pragma unroll
                for (int n = 0; n < 2; ++n) {
                    acc[mh * 4 + m][nh * 2 + n] = __builtin_amdgcn_mfma_f32_16x16x32_bf16(
                        af[m][0], bfr[n][0], acc[mh * 4 + m][nh * 2 + n], 0, 0, 0);
                    acc[mh * 4 + m][nh * 2 + n] = __builtin_amdgcn_mfma_f32_16x16x32_bf16(
                        af[m][1], bfr[n][1], acc[mh * 4 + m][nh * 2 + n], 0, 0, 0);
                }
            __builtin_amdgcn_s_setprio(0);

            if (qd == 0 && t + 1 < NT) {         // stage B of tile t+1
                #pragma unroll
                for (int q = 0; q < 4; ++q)
                    gload16(bSrc[q] + koff, ldsE + nBufE + 16384 + dstE[q]);
            }
        }
        buf ^= 1;
    }

    // epilogue: out -= 2*acc  (fp32 atomics; split-K partials race benignly)
    #pragma unroll
    for (int mi = 0; mi < 8; ++mi) {
        #pragma unroll
        for (int ni = 0; ni < 4; ++ni) {
            #pragma unroll
            for (int jj = 0; jj < 4; ++jj) {
                const int R = rowBase + wr * 128 + mi * 16 + (lane >> 4) * 4 + jj;
                const int Cc = colBase + wc * 64 + ni * 16 + (lane & 15);
                atomicAdd(&out[(size_t)R * kNY + Cc], -2.0f * acc[mi][ni][jj]);
            }
        }
    }
}

} // namespace

extern "C" void kernel_launch(void* const* d_in, const int* in_sizes, int n_in,
                              void* d_out, int out_size, void* d_ws, size_t ws_size,
                              hipStream_t stream) {
    const float* X = (const float*)d_in[0];
    const float* Y = (const float*)d_in[1];
    const float* pi = (const float*)d_in[2];
    const int* classe = (const int*)d_in[3];
    float* out = (float*)d_out;

    char* ws = (char*)d_ws;
    __hip_bfloat16* YB = (__hip_bfloat16*)(ws + OFF_YB);
    __hip_bfloat16* XPB = (__hip_bfloat16*)(ws + OFF_XP);
    int* ts = (int*)(ws + OFF_TS);
    int* te = (int*)(ws + OFF_TE);
    float* C1 = (float*)(ws + OFF_C1);
    float* C2 = (float*)(ws + OFF_C2);

    init_ranges<<<(kC * kTP + 255) / 256, 256, 0, stream>>>(ts, te, C1);
    pi_scan<<<dim3(kT / 64, kC), kTP, 0, stream>>>(pi, ts, te);
    prep_main<<<kNY + kNX * 8, 256, 0, stream>>>(Y, X, classe, ts, te, YB, XPB, C1, C2);
    init_out<<<kNX, 256, 0, stream>>>(C1, C2, classe, out);
    gemm_c3<<<(kNX / 256) * (kNY / 256) * SPLITK, 512, 0, stream>>>(XPB, YB, out);
}